// Round 10
// baseline (103.006 us; speedup 1.0000x reference)
//
#include <hip/hip_runtime.h>

#define EPSM 1e-3f
#define KLOG2E 2.8853900817779268f   // 2*log2(e): folded into layer-1 weights

typedef __fp16 h2 __attribute__((ext_vector_type(2)));
typedef __attribute__((address_space(4))) const float cfloat;  // constant AS -> s_load

__device__ __forceinline__ h2 as_h2(float f){ union U{float f; h2 h;} u; u.f = f; return u.h; }
__device__ __forceinline__ float h2_bits(h2 h){ union U{h2 h; float f;} u; u.h = h; return u.f; }

__device__ __forceinline__ float fdot2f(h2 a, h2 b, float c){
#if __has_builtin(__builtin_amdgcn_fdot2)
    return __builtin_amdgcn_fdot2(a, b, c, false);
#else
    return fmaf((float)a.x, (float)b.x, fmaf((float)a.y, (float)b.y, c));
#endif
}
__device__ __forceinline__ h2 pkrtz(float a, float b){
#if __has_builtin(__builtin_amdgcn_cvt_pkrtz)
    return __builtin_amdgcn_cvt_pkrtz(a, b);
#else
    h2 r; r.x = (__fp16)a; r.y = (__fp16)b; return r;
#endif
}
__device__ __forceinline__ float aexp2(float x){
#if __has_builtin(__builtin_amdgcn_exp2f)
    return __builtin_amdgcn_exp2f(x);
#else
    return __expf(0.6931471805599453f * x);
#endif
}
__device__ __forceinline__ float arcp(float x){
#if __has_builtin(__builtin_amdgcn_rcpf)
    return __builtin_amdgcn_rcpf(x);
#else
    return 1.0f / x;
#endif
}
// mass-path tanh (R5-validated): a = 2*log2(e)*x pre-scaled; exp + v_rcp.
__device__ __forceinline__ float tanh_s(float a){
    float t = aexp2(a);
    float r = arcp(t + 1.0f);
    return fmaf(-2.0f, r, 1.0f);
}
// rhs-path tanh PAIR with ONE shared trans-free reciprocal:
// h_i = 1 - 2/(1+2^{a_i}). Replaces 2x v_rcp (32 cyc) with ~10 VALU (20 cyc).
// fminf(a,60) guard: p_i <= 2^60+1 so m = p0*p1 <= ~2^121 (no inf -> seed safe);
// negative args are inherently safe (exp2->0, p->1). Int-seed + 2 Newton:
// abs err <= ~1.2e-4, below the existing f16-pack rounding (5e-4).
// (Numerically validated: same seed+2-Newton passed in R6 mass path, absmax 32.)
__device__ __forceinline__ void tanh2_shared(float a0, float a1, float& h0, float& h1){
    float t0 = aexp2(fminf(a0, 60.0f));
    float t1 = aexp2(fminf(a1, 60.0f));
    float p0 = t0 + 1.0f, p1 = t1 + 1.0f;
    float m  = p0 * p1;
    union { float f; unsigned u; } s; s.f = m; s.u = 0x7EF311C3u - s.u;
    float r = s.f;
    r = r * fmaf(-m, r, 2.0f);
    r = r * fmaf(-m, r, 2.0f);
    h0 = fmaf(-2.0f, r * p1, 1.0f);
    h1 = fmaf(-2.0f, r * p0, 1.0f);
}

__device__ __forceinline__ float h2f(float a, float b){
    h2 h; h.x = (__fp16)a; h.y = (__fp16)b; return h2_bits(h);
}

// ---------------------------------------------------------------------------
// Per neuron-PAIR record: 40 floats (R5 layout). Mass MLP fp32; rhs MLPs
// packed f16 with f32 accumulation. L1 weights/biases pre-scaled by 2*log2(e).
// Weights read via constant-AS scalar loads (SGPRs).
// ---------------------------------------------------------------------------
__global__ void phynn_pack(const float* __restrict__ Wm1, const float* __restrict__ bm1,
                           const float* __restrict__ Wm2, const float* __restrict__ bm2,
                           const float* __restrict__ Wc1, const float* __restrict__ bc1,
                           const float* __restrict__ Wc2, const float* __restrict__ bc2,
                           const float* __restrict__ Wg1, const float* __restrict__ bg1,
                           const float* __restrict__ Wg2, const float* __restrict__ bg2,
                           const float* __restrict__ Wt1, const float* __restrict__ bt1,
                           const float* __restrict__ Wt2, const float* __restrict__ bt2,
                           float* __restrict__ P)
{
    const float k = KLOG2E;
    int p = threadIdx.x;
    if (p < 64) {
        int n0 = 2*p, n1 = 2*p + 1;
        float* o = P + p * 40;
        o[0]  = k*Wm1[2*n0];   o[1]  = k*Wm1[2*n0+1]; o[2]  = k*bm1[n0];     o[3]  = Wm2[n0];
        o[4]  = Wm2[256+n0];   o[5]  = Wm2[384+n0];   o[6]  = k*Wm1[2*n1];   o[7]  = k*Wm1[2*n1+1];
        o[8]  = k*bm1[n1];     o[9]  = Wm2[n1];       o[10] = Wm2[256+n1];   o[11] = Wm2[384+n1];
        o[12] = h2f(k*Wg1[2*n0], k*Wg1[2*n0+1]);
        o[13] = h2f(k*Wg1[2*n1], k*Wg1[2*n1+1]);
        o[14] = k*bg1[n0];     o[15] = k*bg1[n1];
        o[16] = h2f(Wg2[n0],      Wg2[n1]);
        o[17] = h2f(Wg2[128+n0],  Wg2[128+n1]);
        o[18] = h2f(k*Wc1[4*n0],   k*Wc1[4*n0+1]);
        o[19] = h2f(k*Wc1[4*n0+2], k*Wc1[4*n0+3]);
        o[20] = h2f(k*Wc1[4*n1],   k*Wc1[4*n1+1]);
        o[21] = h2f(k*Wc1[4*n1+2], k*Wc1[4*n1+3]);
        o[22] = k*bc1[n0];     o[23] = k*bc1[n1];
        o[24] = h2f(Wc2[n0],      Wc2[n1]);
        o[25] = h2f(Wc2[128+n0],  Wc2[128+n1]);
        o[26] = h2f(Wc2[256+n0],  Wc2[256+n1]);
        o[27] = h2f(Wc2[384+n0],  Wc2[384+n1]);
        o[28] = h2f(k*Wt1[6*n0],   k*Wt1[6*n0+1]);
        o[29] = h2f(k*Wt1[6*n0+2], k*Wt1[6*n0+3]);
        o[30] = h2f(k*Wt1[6*n0+4], k*Wt1[6*n0+5]);
        o[31] = k*bt1[n0];
        o[32] = h2f(k*Wt1[6*n1],   k*Wt1[6*n1+1]);
        o[33] = h2f(k*Wt1[6*n1+2], k*Wt1[6*n1+3]);
        o[34] = h2f(k*Wt1[6*n1+4], k*Wt1[6*n1+5]);
        o[35] = k*bt1[n1];
        o[36] = h2f(Wt2[n0],     Wt2[n1]);
        o[37] = h2f(Wt2[128+n0], Wt2[128+n1]);
        o[38] = 0.f; o[39] = 0.f;
    }
    if (p == 64) {
        float* t = P + 2560;
        t[0] = bm2[0]; t[1] = bm2[1]; t[2]  = bm2[2]; t[3]  = bm2[3];
        t[4] = bc2[0]; t[5] = bc2[1]; t[6]  = bc2[2]; t[7]  = bc2[3];
        t[8] = bg2[0]; t[9] = bg2[1]; t[10] = bt2[0]; t[11] = bt2[1];
    }
}

#define NPE 2

__global__ __launch_bounds__(256, 4) void phynn_main(
    const float2* __restrict__ q, const float2* __restrict__ qd, const float2* __restrict__ u,
    const float* __restrict__ P, float* __restrict__ out, int B)
{
    cfloat* W = (cfloat*)(unsigned long long)P;

    const int half = B >> 1;
    const int tid  = blockIdx.x * 256 + threadIdx.x;
    if (tid >= half) return;

    int e[NPE];
    e[0] = tid;
    e[1] = tid + half;

    float q0[NPE], q1[NPE], d0[NPE], d1[NPE], u0[NPE], u1[NPE];
    h2 qh[NPE], dh[NPE], uh[NPE];
    #pragma unroll
    for (int s = 0; s < NPE; ++s) {
        float2 vq = q[e[s]];  q0[s] = vq.x; q1[s] = vq.y;
        float2 vd = qd[e[s]]; d0[s] = vd.x; d1[s] = vd.y;
        float2 vu = u[e[s]];  u0[s] = vu.x; u1[s] = vu.y;
        qh[s] = pkrtz(q0[s], q1[s]);
        dh[s] = pkrtz(d0[s], d1[s]);
        uh[s] = pkrtz(u0[s], u1[s]);
    }

    float aL0[NPE] = {}, aL2[NPE] = {}, aL3[NPE] = {};
    float aC0[NPE] = {}, aC1[NPE] = {}, aC2[NPE] = {}, aC3[NPE] = {};
    float aG0[NPE] = {}, aG1[NPE] = {};
    float aT0[NPE] = {}, aT1[NPE] = {};

    #pragma unroll 2
    for (int p = 0; p < 64; ++p) {
        cfloat* w = W + p * 40;
        const float w0  = w[0],  w1  = w[1],  w2  = w[2],  w3  = w[3];
        const float w4  = w[4],  w5  = w[5],  w6  = w[6],  w7  = w[7];
        const float w8  = w[8],  w9  = w[9],  w10 = w[10], w11 = w[11];
        const float w12 = w[12], w13 = w[13], w14 = w[14], w15 = w[15];
        const float w16 = w[16], w17 = w[17], w18 = w[18], w19 = w[19];
        const float w20 = w[20], w21 = w[21], w22 = w[22], w23 = w[23];
        const float w24 = w[24], w25 = w[25], w26 = w[26], w27 = w[27];
        const float w28 = w[28], w29 = w[29], w30 = w[30], w31 = w[31];
        const float w32 = w[32], w33 = w[33], w34 = w[34], w35 = w[35];
        const float w36 = w[36], w37 = w[37];

        const h2 gw0 = as_h2(w12), gw1 = as_h2(w13);
        const h2 gl0 = as_h2(w16), gl1 = as_h2(w17);
        const h2 c0a = as_h2(w18), c0b = as_h2(w19);
        const h2 c1a = as_h2(w20), c1b = as_h2(w21);
        const h2 cl0 = as_h2(w24), cl1 = as_h2(w25), cl2 = as_h2(w26), cl3 = as_h2(w27);
        const h2 t0a = as_h2(w28), t0b = as_h2(w29), t0c = as_h2(w30);
        const h2 t1a = as_h2(w32), t1b = as_h2(w33), t1c = as_h2(w34);
        const h2 tl0 = as_h2(w36), tl1 = as_h2(w37);

        #pragma unroll
        for (int s = 0; s < NPE; ++s) {
            // mass MLP — fp32, untouched R5 path
            float am0 = fmaf(w0, q0[s], fmaf(w1, q1[s], w2));
            float am1 = fmaf(w6, q0[s], fmaf(w7, q1[s], w8));
            float hm0 = tanh_s(am0);
            float hm1 = tanh_s(am1);
            aL0[s] = fmaf(w3,  hm0, fmaf(w9,  hm1, aL0[s]));
            aL2[s] = fmaf(w4,  hm0, fmaf(w10, hm1, aL2[s]));
            aL3[s] = fmaf(w5,  hm0, fmaf(w11, hm1, aL3[s]));
            // gravity MLP — f16 dot2, pair-shared reciprocal tanh
            float ag0 = fdot2f(gw0, qh[s], w14);
            float ag1 = fdot2f(gw1, qh[s], w15);
            float hg0, hg1;
            tanh2_shared(ag0, ag1, hg0, hg1);
            h2 hg = pkrtz(hg0, hg1);
            aG0[s] = fdot2f(gl0, hg, aG0[s]);
            aG1[s] = fdot2f(gl1, hg, aG1[s]);
            // Coriolis MLP — f16 dot2, pair-shared reciprocal tanh
            float ac0 = fdot2f(c0a, qh[s], fdot2f(c0b, dh[s], w22));
            float ac1 = fdot2f(c1a, qh[s], fdot2f(c1b, dh[s], w23));
            float hc0, hc1;
            tanh2_shared(ac0, ac1, hc0, hc1);
            h2 hc = pkrtz(hc0, hc1);
            aC0[s] = fdot2f(cl0, hc, aC0[s]);
            aC1[s] = fdot2f(cl1, hc, aC1[s]);
            aC2[s] = fdot2f(cl2, hc, aC2[s]);
            aC3[s] = fdot2f(cl3, hc, aC3[s]);
            // torque MLP — f16 dot2, pair-shared reciprocal tanh
            float at0 = fdot2f(t0a, qh[s], fdot2f(t0b, dh[s], fdot2f(t0c, uh[s], w31)));
            float at1 = fdot2f(t1a, qh[s], fdot2f(t1b, dh[s], fdot2f(t1c, uh[s], w35)));
            float ht0, ht1;
            tanh2_shared(at0, at1, ht0, ht1);
            h2 ht = pkrtz(ht0, ht1);
            aT0[s] = fdot2f(tl0, ht, aT0[s]);
            aT1[s] = fdot2f(tl1, ht, aT1[s]);
        }
    }

    cfloat* bt_ = W + 2560;
    const float bm2x = bt_[0], bm2z = bt_[2], bm2w = bt_[3];
    const float bc2x = bt_[4], bc2y = bt_[5], bc2z = bt_[6], bc2w = bt_[7];
    const float bg2x = bt_[8], bg2y = bt_[9], bt2x = bt_[10], bt2y = bt_[11];

    float*  outf  = out;
    float2* o_qdd = (float2*)outf;
    float4* o_M   = (float4*)(outf + (size_t)2 * B);
    float4* o_C   = (float4*)(outf + (size_t)6 * B);
    float2* o_g   = (float2*)(outf + (size_t)10 * B);
    float2* o_t   = (float2*)(outf + (size_t)12 * B);

    #pragma unroll
    for (int s = 0; s < NPE; ++s) {
        float l00 = aL0[s] + bm2x;
        float l10 = aL2[s] + bm2z;
        float l11 = aL3[s] + bm2w;
        float M00 = fmaf(l00, l00, EPSM);
        float M01 = l00 * l10;
        float M11 = fmaf(l10, l10, fmaf(l11, l11, EPSM));

        float C00 = aC0[s] + bc2x;
        float C01 = aC1[s] + bc2y;
        float C10 = aC2[s] + bc2z;
        float C11 = aC3[s] + bc2w;

        float g0 = aG0[s] + bg2x;
        float g1 = aG1[s] + bg2y;
        float t0 = aT0[s] + bt2x;
        float t1 = aT1[s] + bt2y;

        float rhs0 = u0[s] - fmaf(C00, d0[s], C01 * d1[s]) - g0 - t0;
        float rhs1 = u1[s] - fmaf(C10, d0[s], C11 * d1[s]) - g1 - t1;

        float det = fmaf(M00, M11, -(M01 * M01));
        float r0  = arcp(det);
        float rdet = r0 * fmaf(-det, r0, 2.0f);  // one Newton step
        float qdd0 = fmaf(M11, rhs0, -(M01 * rhs1)) * rdet;
        float qdd1 = fmaf(M00, rhs1, -(M01 * rhs0)) * rdet;

        o_qdd[e[s]] = make_float2(qdd0, qdd1);
        o_M[e[s]]   = make_float4(M00, M01, M01, M11);
        o_C[e[s]]   = make_float4(C00, C01, C10, C11);
        o_g[e[s]]   = make_float2(g0, g1);
        o_t[e[s]]   = make_float2(t0, t1);
    }
}

extern "C" void kernel_launch(void* const* d_in, const int* in_sizes, int n_in,
                              void* d_out, int out_size, void* d_ws, size_t ws_size,
                              hipStream_t stream)
{
    const float* q   = (const float*)d_in[0];
    const float* qd  = (const float*)d_in[1];
    const float* u   = (const float*)d_in[2];
    const float* Wm1 = (const float*)d_in[3];
    const float* bm1 = (const float*)d_in[4];
    const float* Wm2 = (const float*)d_in[5];
    const float* bm2 = (const float*)d_in[6];
    const float* Wc1 = (const float*)d_in[7];
    const float* bc1 = (const float*)d_in[8];
    const float* Wc2 = (const float*)d_in[9];
    const float* bc2 = (const float*)d_in[10];
    const float* Wg1 = (const float*)d_in[11];
    const float* bg1 = (const float*)d_in[12];
    const float* Wg2 = (const float*)d_in[13];
    const float* bg2 = (const float*)d_in[14];
    const float* Wt1 = (const float*)d_in[15];
    const float* bt1 = (const float*)d_in[16];
    const float* Wt2 = (const float*)d_in[17];
    const float* bt2 = (const float*)d_in[18];

    const int B = in_sizes[0] / 2;
    float* P = (float*)d_ws;  // 2560 + 12 floats

    hipLaunchKernelGGL(phynn_pack, dim3(1), dim3(128), 0, stream,
                       Wm1, bm1, Wm2, bm2, Wc1, bc1, Wc2, bc2,
                       Wg1, bg1, Wg2, bg2, Wt1, bt1, Wt2, bt2, P);

    const int half   = B / 2;
    const int blocks = (half + 255) / 256;
    hipLaunchKernelGGL(phynn_main, dim3(blocks), dim3(256), 0, stream,
                       (const float2*)q, (const float2*)qd, (const float2*)u,
                       P, (float*)d_out, B);
}

// Round 11
// 90.712 us; speedup vs baseline: 1.1355x; 1.1355x over previous
//
#include <hip/hip_runtime.h>

#define HID 128
#define EPSM 1e-3f
#define KLOG2E 2.8853900817779268f   // 2*log2(e): folded into layer-1 weights

typedef __fp16 h2 __attribute__((ext_vector_type(2)));
typedef __attribute__((address_space(4))) const float cfloat;  // constant AS -> s_load

__device__ __forceinline__ h2 as_h2(float f){ union U{float f; h2 h;} u; u.f = f; return u.h; }
__device__ __forceinline__ float h2_bits(h2 h){ union U{h2 h; float f;} u; u.h = h; return u.f; }

__device__ __forceinline__ float fdot2f(h2 a, h2 b, float c){
#if __has_builtin(__builtin_amdgcn_fdot2)
    return __builtin_amdgcn_fdot2(a, b, c, false);
#else
    return fmaf((float)a.x, (float)b.x, fmaf((float)a.y, (float)b.y, c));
#endif
}
__device__ __forceinline__ h2 pkrtz(float a, float b){
#if __has_builtin(__builtin_amdgcn_cvt_pkrtz)
    return __builtin_amdgcn_cvt_pkrtz(a, b);
#else
    h2 r; r.x = (__fp16)a; r.y = (__fp16)b; return r;
#endif
}
__device__ __forceinline__ float aexp2(float x){
#if __has_builtin(__builtin_amdgcn_exp2f)
    return __builtin_amdgcn_exp2f(x);
#else
    return __expf(0.6931471805599453f * x);
#endif
}
__device__ __forceinline__ float arcp(float x){
#if __has_builtin(__builtin_amdgcn_rcpf)
    return __builtin_amdgcn_rcpf(x);
#else
    return 1.0f / x;
#endif
}
// tanh(x) where a = 2*log2(e)*x is the pre-scaled argument
__device__ __forceinline__ float tanh_s(float a){
    float t = aexp2(a);
    float r = arcp(t + 1.0f);
    return fmaf(-2.0f, r, 1.0f);
}

__device__ __forceinline__ float h2f(float a, float b){
    h2 h; h.x = (__fp16)a; h.y = (__fp16)b; return h2_bits(h);
}

// ---------------------------------------------------------------------------
// Per neuron-PAIR record: 40 floats. Mass MLP stays fp32 (feeds the SPD
// solve; M-errors amplify ~1e6x). grav/cor/torque use packed f16 with f32
// accumulation via v_dot2_f32_f16. Layer-1 weights/biases pre-scaled by
// 2*log2(e). Main kernel reads this table via SMEM (s_load) — wave-uniform.
// ---------------------------------------------------------------------------
__global__ void phynn_pack(const float* __restrict__ Wm1, const float* __restrict__ bm1,
                           const float* __restrict__ Wm2, const float* __restrict__ bm2,
                           const float* __restrict__ Wc1, const float* __restrict__ bc1,
                           const float* __restrict__ Wc2, const float* __restrict__ bc2,
                           const float* __restrict__ Wg1, const float* __restrict__ bg1,
                           const float* __restrict__ Wg2, const float* __restrict__ bg2,
                           const float* __restrict__ Wt1, const float* __restrict__ bt1,
                           const float* __restrict__ Wt2, const float* __restrict__ bt2,
                           float* __restrict__ P)
{
    const float k = KLOG2E;
    int p = threadIdx.x;
    if (p < 64) {
        int n0 = 2*p, n1 = 2*p + 1;
        float* o = P + p * 40;
        o[0]  = k*Wm1[2*n0];   o[1]  = k*Wm1[2*n0+1]; o[2]  = k*bm1[n0];     o[3]  = Wm2[n0];
        o[4]  = Wm2[256+n0];   o[5]  = Wm2[384+n0];   o[6]  = k*Wm1[2*n1];   o[7]  = k*Wm1[2*n1+1];
        o[8]  = k*bm1[n1];     o[9]  = Wm2[n1];       o[10] = Wm2[256+n1];   o[11] = Wm2[384+n1];
        o[12] = h2f(k*Wg1[2*n0], k*Wg1[2*n0+1]);
        o[13] = h2f(k*Wg1[2*n1], k*Wg1[2*n1+1]);
        o[14] = k*bg1[n0];     o[15] = k*bg1[n1];
        o[16] = h2f(Wg2[n0],      Wg2[n1]);
        o[17] = h2f(Wg2[128+n0],  Wg2[128+n1]);
        o[18] = h2f(k*Wc1[4*n0],   k*Wc1[4*n0+1]);
        o[19] = h2f(k*Wc1[4*n0+2], k*Wc1[4*n0+3]);
        o[20] = h2f(k*Wc1[4*n1],   k*Wc1[4*n1+1]);
        o[21] = h2f(k*Wc1[4*n1+2], k*Wc1[4*n1+3]);
        o[22] = k*bc1[n0];     o[23] = k*bc1[n1];
        o[24] = h2f(Wc2[n0],      Wc2[n1]);
        o[25] = h2f(Wc2[128+n0],  Wc2[128+n1]);
        o[26] = h2f(Wc2[256+n0],  Wc2[256+n1]);
        o[27] = h2f(Wc2[384+n0],  Wc2[384+n1]);
        o[28] = h2f(k*Wt1[6*n0],   k*Wt1[6*n0+1]);
        o[29] = h2f(k*Wt1[6*n0+2], k*Wt1[6*n0+3]);
        o[30] = h2f(k*Wt1[6*n0+4], k*Wt1[6*n0+5]);
        o[31] = k*bt1[n0];
        o[32] = h2f(k*Wt1[6*n1],   k*Wt1[6*n1+1]);
        o[33] = h2f(k*Wt1[6*n1+2], k*Wt1[6*n1+3]);
        o[34] = h2f(k*Wt1[6*n1+4], k*Wt1[6*n1+5]);
        o[35] = k*bt1[n1];
        o[36] = h2f(Wt2[n0],     Wt2[n1]);
        o[37] = h2f(Wt2[128+n0], Wt2[128+n1]);
        o[38] = 0.f; o[39] = 0.f;
    }
    if (p == 64) {
        float* t = P + 2560;
        t[0] = bm2[0]; t[1] = bm2[1]; t[2]  = bm2[2]; t[3]  = bm2[3];
        t[4] = bc2[0]; t[5] = bc2[1]; t[6]  = bc2[2]; t[7]  = bc2[3];
        t[8] = bg2[0]; t[9] = bg2[1]; t[10] = bt2[0]; t[11] = bt2[1];
    }
}

#define NPE 2

__global__ __launch_bounds__(256, 4) void phynn_main(
    const float2* __restrict__ q, const float2* __restrict__ qd, const float2* __restrict__ u,
    const float* __restrict__ P, float* __restrict__ out, int B)
{
    // Weight table through constant addrspace: uniform scalar loads -> SMEM,
    // fields live in SGPRs, zero LDS / zero vector-VMEM traffic.
    cfloat* W = (cfloat*)(unsigned long long)P;

    const int half = B >> 1;
    const int tid  = blockIdx.x * 256 + threadIdx.x;
    if (tid >= half) return;

    int e[NPE];
    e[0] = tid;
    e[1] = tid + half;

    float q0[NPE], q1[NPE], d0[NPE], d1[NPE], u0[NPE], u1[NPE];
    h2 qh[NPE], dh[NPE], uh[NPE];
    #pragma unroll
    for (int s = 0; s < NPE; ++s) {
        float2 vq = q[e[s]];  q0[s] = vq.x; q1[s] = vq.y;
        float2 vd = qd[e[s]]; d0[s] = vd.x; d1[s] = vd.y;
        float2 vu = u[e[s]];  u0[s] = vu.x; u1[s] = vu.y;
        qh[s] = pkrtz(q0[s], q1[s]);
        dh[s] = pkrtz(d0[s], d1[s]);
        uh[s] = pkrtz(u0[s], u1[s]);
    }

    float aL0[NPE] = {}, aL2[NPE] = {}, aL3[NPE] = {};
    float aC0[NPE] = {}, aC1[NPE] = {}, aC2[NPE] = {}, aC3[NPE] = {};
    float aG0[NPE] = {}, aG1[NPE] = {};
    float aT0[NPE] = {}, aT1[NPE] = {};

    #pragma unroll 2
    for (int p = 0; p < 64; ++p) {
        cfloat* w = W + p * 40;
        const float w0  = w[0],  w1  = w[1],  w2  = w[2],  w3  = w[3];
        const float w4  = w[4],  w5  = w[5],  w6  = w[6],  w7  = w[7];
        const float w8  = w[8],  w9  = w[9],  w10 = w[10], w11 = w[11];
        const float w12 = w[12], w13 = w[13], w14 = w[14], w15 = w[15];
        const float w16 = w[16], w17 = w[17], w18 = w[18], w19 = w[19];
        const float w20 = w[20], w21 = w[21], w22 = w[22], w23 = w[23];
        const float w24 = w[24], w25 = w[25], w26 = w[26], w27 = w[27];
        const float w28 = w[28], w29 = w[29], w30 = w[30], w31 = w[31];
        const float w32 = w[32], w33 = w[33], w34 = w[34], w35 = w[35];
        const float w36 = w[36], w37 = w[37];

        const h2 gw0 = as_h2(w12), gw1 = as_h2(w13);
        const h2 gl0 = as_h2(w16), gl1 = as_h2(w17);
        const h2 c0a = as_h2(w18), c0b = as_h2(w19);
        const h2 c1a = as_h2(w20), c1b = as_h2(w21);
        const h2 cl0 = as_h2(w24), cl1 = as_h2(w25), cl2 = as_h2(w26), cl3 = as_h2(w27);
        const h2 t0a = as_h2(w28), t0b = as_h2(w29), t0c = as_h2(w30);
        const h2 t1a = as_h2(w32), t1b = as_h2(w33), t1c = as_h2(w34);
        const h2 tl0 = as_h2(w36), tl1 = as_h2(w37);

        #pragma unroll
        for (int s = 0; s < NPE; ++s) {
            // mass MLP — fp32
            float am0 = fmaf(w0, q0[s], fmaf(w1, q1[s], w2));
            float am1 = fmaf(w6, q0[s], fmaf(w7, q1[s], w8));
            float hm0 = tanh_s(am0);
            float hm1 = tanh_s(am1);
            aL0[s] = fmaf(w3,  hm0, fmaf(w9,  hm1, aL0[s]));
            aL2[s] = fmaf(w4,  hm0, fmaf(w10, hm1, aL2[s]));
            aL3[s] = fmaf(w5,  hm0, fmaf(w11, hm1, aL3[s]));
            // gravity MLP — f16 dot2
            float ag0 = fdot2f(gw0, qh[s], w14);
            float ag1 = fdot2f(gw1, qh[s], w15);
            h2 hg = pkrtz(tanh_s(ag0), tanh_s(ag1));
            aG0[s] = fdot2f(gl0, hg, aG0[s]);
            aG1[s] = fdot2f(gl1, hg, aG1[s]);
            // Coriolis MLP — f16 dot2
            float ac0 = fdot2f(c0a, qh[s], fdot2f(c0b, dh[s], w22));
            float ac1 = fdot2f(c1a, qh[s], fdot2f(c1b, dh[s], w23));
            h2 hc = pkrtz(tanh_s(ac0), tanh_s(ac1));
            aC0[s] = fdot2f(cl0, hc, aC0[s]);
            aC1[s] = fdot2f(cl1, hc, aC1[s]);
            aC2[s] = fdot2f(cl2, hc, aC2[s]);
            aC3[s] = fdot2f(cl3, hc, aC3[s]);
            // torque MLP — f16 dot2
            float at0 = fdot2f(t0a, qh[s], fdot2f(t0b, dh[s], fdot2f(t0c, uh[s], w31)));
            float at1 = fdot2f(t1a, qh[s], fdot2f(t1b, dh[s], fdot2f(t1c, uh[s], w35)));
            h2 ht = pkrtz(tanh_s(at0), tanh_s(at1));
            aT0[s] = fdot2f(tl0, ht, aT0[s]);
            aT1[s] = fdot2f(tl1, ht, aT1[s]);
        }
    }

    cfloat* bt_ = W + 2560;
    const float bm2x = bt_[0], bm2z = bt_[2], bm2w = bt_[3];
    const float bc2x = bt_[4], bc2y = bt_[5], bc2z = bt_[6], bc2w = bt_[7];
    const float bg2x = bt_[8], bg2y = bt_[9], bt2x = bt_[10], bt2y = bt_[11];

    float*  outf  = out;
    float2* o_qdd = (float2*)outf;
    float4* o_M   = (float4*)(outf + (size_t)2 * B);
    float4* o_C   = (float4*)(outf + (size_t)6 * B);
    float2* o_g   = (float2*)(outf + (size_t)10 * B);
    float2* o_t   = (float2*)(outf + (size_t)12 * B);

    #pragma unroll
    for (int s = 0; s < NPE; ++s) {
        float l00 = aL0[s] + bm2x;
        float l10 = aL2[s] + bm2z;
        float l11 = aL3[s] + bm2w;
        float M00 = fmaf(l00, l00, EPSM);
        float M01 = l00 * l10;
        float M11 = fmaf(l10, l10, fmaf(l11, l11, EPSM));

        float C00 = aC0[s] + bc2x;
        float C01 = aC1[s] + bc2y;
        float C10 = aC2[s] + bc2z;
        float C11 = aC3[s] + bc2w;

        float g0 = aG0[s] + bg2x;
        float g1 = aG1[s] + bg2y;
        float t0 = aT0[s] + bt2x;
        float t1 = aT1[s] + bt2y;

        float rhs0 = u0[s] - fmaf(C00, d0[s], C01 * d1[s]) - g0 - t0;
        float rhs1 = u1[s] - fmaf(C10, d0[s], C11 * d1[s]) - g1 - t1;

        float det = fmaf(M00, M11, -(M01 * M01));
        float r0  = arcp(det);
        float rdet = r0 * fmaf(-det, r0, 2.0f);  // one Newton step: ~1e-12 rel
        float qdd0 = fmaf(M11, rhs0, -(M01 * rhs1)) * rdet;
        float qdd1 = fmaf(M00, rhs1, -(M01 * rhs0)) * rdet;

        o_qdd[e[s]] = make_float2(qdd0, qdd1);
        o_M[e[s]]   = make_float4(M00, M01, M01, M11);
        o_C[e[s]]   = make_float4(C00, C01, C10, C11);
        o_g[e[s]]   = make_float2(g0, g1);
        o_t[e[s]]   = make_float2(t0, t1);
    }
}

extern "C" void kernel_launch(void* const* d_in, const int* in_sizes, int n_in,
                              void* d_out, int out_size, void* d_ws, size_t ws_size,
                              hipStream_t stream)
{
    const float* q   = (const float*)d_in[0];
    const float* qd  = (const float*)d_in[1];
    const float* u   = (const float*)d_in[2];
    const float* Wm1 = (const float*)d_in[3];
    const float* bm1 = (const float*)d_in[4];
    const float* Wm2 = (const float*)d_in[5];
    const float* bm2 = (const float*)d_in[6];
    const float* Wc1 = (const float*)d_in[7];
    const float* bc1 = (const float*)d_in[8];
    const float* Wc2 = (const float*)d_in[9];
    const float* bc2 = (const float*)d_in[10];
    const float* Wg1 = (const float*)d_in[11];
    const float* bg1 = (const float*)d_in[12];
    const float* Wg2 = (const float*)d_in[13];
    const float* bg2 = (const float*)d_in[14];
    const float* Wt1 = (const float*)d_in[15];
    const float* bt1 = (const float*)d_in[16];
    const float* Wt2 = (const float*)d_in[17];
    const float* bt2 = (const float*)d_in[18];

    const int B = in_sizes[0] / 2;
    float* P = (float*)d_ws;  // 2560 + 12 floats

    hipLaunchKernelGGL(phynn_pack, dim3(1), dim3(128), 0, stream,
                       Wm1, bm1, Wm2, bm2, Wc1, bc1, Wc2, bc2,
                       Wg1, bg1, Wg2, bg2, Wt1, bt1, Wt2, bt2, P);

    const int half   = B / 2;
    const int blocks = (half + 255) / 256;
    hipLaunchKernelGGL(phynn_main, dim3(blocks), dim3(256), 0, stream,
                       (const float2*)q, (const float2*)qd, (const float2*)u,
                       P, (float*)d_out, B);
}